// Round 3
// baseline (912.096 us; speedup 1.0000x reference)
//
#include <hip/hip_runtime.h>
#include <hip/hip_bf16.h>
#include <stdint.h>
#include <stddef.h>

#define T_STEPS 28
#define I_DIM 28
#define H_DIM 64
#define O_DIM 10
#define BT 64   // batch rows per block

typedef short bf16x8 __attribute__((ext_vector_type(8)));
typedef float f32x4  __attribute__((ext_vector_type(4)));

__device__ __forceinline__ short f2bf(float f){
    uint32_t u = __builtin_bit_cast(uint32_t, f);
    u = (u + 0x7fffu + ((u >> 16) & 1u)) >> 16;
    return (short)u;
}
__device__ __forceinline__ float bf2f(short v){
    return __builtin_bit_cast(float, (uint32_t)(uint16_t)v << 16);
}
__device__ __forceinline__ float sigmoid_fast(float x){
    return __builtin_amdgcn_rcpf(1.0f + __builtin_amdgcn_exp2f(-1.4426950408889634f * x));
}
__device__ __forceinline__ float tanh_fast(float x){
    return 1.0f - 2.0f * __builtin_amdgcn_rcpf(1.0f + __builtin_amdgcn_exp2f(2.8853900817779268f * x));
}

// LDS layout (bytes):
//   x0: short[64][40] @ 0      (5120)   x tile, t even
//   x1: short[64][40] @ 5120   (5120)   x tile, t odd
//   h0: short[64][72] @ 10240  (9216)   h state buffer 0 (also final h for out-proj)
//   h1: short[64][72] @ 19456  (9216)   h state buffer 1
//   wout_t: float[640] @ 28672 (2560)
//   bout_s: float[12]  @ 31232 (48)
#define X_OFF(b)  ((b) * 5120)
#define H_OFF(b)  (10240 + (b) * 9216)
#define SMEM_BYTES (31232 + 48)

__global__ __launch_bounds__(256, 4)
void lstm_fused(const float* __restrict__ x,
                const float* __restrict__ W_ih,
                const float* __restrict__ W_hh,
                const float* __restrict__ b_ih,
                const float* __restrict__ b_hh,
                const float* __restrict__ W_out,
                const float* __restrict__ b_out,
                float* __restrict__ out)
{
    __shared__ alignas(16) unsigned char smem[SMEM_BYTES];
    float* wout_t = (float*)(smem + 28672);
    float* bout_s = (float*)(smem + 31232);

    const int tid  = threadIdx.x;
    const int w    = tid >> 6;     // wave id 0..3 -> owns hidden cols [16w,16w+16)
    const int lane = tid & 63;
    const int col  = lane & 15;
    const int quad = lane >> 4;
    const int b0   = blockIdx.x * BT;

    // ---- weight B-fragments in registers (once) ----
    // B[k][n]: lane holds n = nt*64 + w*16 + col, k = quad*8 + j
    bf16x8 wih[4];
    bf16x8 whh[2][4];
    float  bias_v[4];
    #pragma unroll
    for (int nt = 0; nt < 4; ++nt){
        const int n = nt * 64 + w * 16 + col;
        #pragma unroll
        for (int j = 0; j < 8; ++j){
            const int k = quad * 8 + j;
            wih[nt][j] = (k < I_DIM) ? f2bf(W_ih[n * I_DIM + k]) : (short)0;
        }
        #pragma unroll
        for (int s = 0; s < 2; ++s)
            #pragma unroll
            for (int j = 0; j < 8; ++j){
                const int k = s * 32 + quad * 8 + j;
                whh[s][nt][j] = f2bf(W_hh[n * H_DIM + k]);
            }
        bias_v[nt] = b_ih[n] + b_hh[n];
    }

    // ---- stage W_out (transposed) + b_out ----
    for (int idx = tid; idx < H_DIM * O_DIM; idx += 256){
        const int j = idx / O_DIM;
        const int o = idx - j * O_DIM;
        wout_t[idx] = W_out[o * H_DIM + j];
    }
    if (tid < O_DIM) bout_s[tid] = b_out[tid];

    // ---- zero h buffer 0 (initial state) ----
    for (int idx = tid; idx < 64 * 72; idx += 256)
        ((short*)(smem + H_OFF(0)))[idx] = 0;

    // ---- x staging: 4 threads per row, 8 cols each (cols 28..31 stay 0 in xa) ----
    const int row = tid >> 2;
    const int seg = tid & 3;
    const float* px = x + (size_t)(b0 + row) * (T_STEPS * I_DIM);

    float xa[8];
    #pragma unroll
    for (int u = 0; u < 8; ++u){
        const int k = seg * 8 + u;
        xa[u] = (k < I_DIM) ? px[k] : 0.0f;   // pad lanes stay 0 forever
    }

    float cst[4][4];
    #pragma unroll
    for (int mt = 0; mt < 4; ++mt)
        #pragma unroll
        for (int r = 0; r < 4; ++r) cst[mt][r] = 0.0f;

    for (int t = 0; t < T_STEPS; ++t){
        short (*xb)[40] = (short(*)[40])(smem + X_OFF(t & 1));
        // stage x(t) (packed bf16x2 b32 stores)
        #pragma unroll
        for (int u = 0; u < 4; ++u){
            float2 p2; p2.x = xa[2*u]; p2.y = xa[2*u+1];
            __hip_bfloat162 p = __float22bfloat162_rn(p2);
            *(__hip_bfloat162*)&xb[row][seg * 8 + 2 * u] = p;
        }
        // prefetch x(t+1)
        if (t < T_STEPS - 1){
            #pragma unroll
            for (int u = 0; u < 8; ++u){
                const int k = seg * 8 + u;
                if (k < I_DIM) xa[u] = px[(t + 1) * I_DIM + k];
            }
        }
        __syncthreads();   // the ONLY barrier per step: x(t) staged, h(t-1) visible

        const short (*hr)[72] = (const short(*)[72])(smem + H_OFF(t & 1));
        short (*hw)[72]       = (short(*)[72])(smem + H_OFF((t + 1) & 1));

        // two halves of the m dimension -> acc live range is 32 regs, not 64
        #pragma unroll
        for (int half = 0; half < 2; ++half){
            f32x4 acc[2][4];
            #pragma unroll
            for (int m = 0; m < 2; ++m)
                #pragma unroll
                for (int nt = 0; nt < 4; ++nt){
                    f32x4 c4;
                    c4[0] = bias_v[nt]; c4[1] = bias_v[nt]; c4[2] = bias_v[nt]; c4[3] = bias_v[nt];
                    acc[m][nt] = c4;
                }

            // x-projection: [32 x 32] @ [32 x 256]
            #pragma unroll
            for (int m = 0; m < 2; ++m){
                const int mt = half * 2 + m;
                bf16x8 a = *(const bf16x8*)&xb[mt * 16 + col][quad * 8];
                #pragma unroll
                for (int nt = 0; nt < 4; ++nt)
                    acc[m][nt] = __builtin_amdgcn_mfma_f32_16x16x32_bf16(a, wih[nt], acc[m][nt], 0, 0, 0);
            }
            // recurrence: [32 x 64] @ [64 x 256]
            #pragma unroll
            for (int s = 0; s < 2; ++s)
                #pragma unroll
                for (int m = 0; m < 2; ++m){
                    const int mt = half * 2 + m;
                    bf16x8 a = *(const bf16x8*)&hr[mt * 16 + col][s * 32 + quad * 8];
                    #pragma unroll
                    for (int nt = 0; nt < 4; ++nt)
                        acc[m][nt] = __builtin_amdgcn_mfma_f32_16x16x32_bf16(a, whh[s][nt], acc[m][nt], 0, 0, 0);
                }

            // activations + cell update; write h straight to the write buffer
            #pragma unroll
            for (int m = 0; m < 2; ++m){
                const int mt = half * 2 + m;
                #pragma unroll
                for (int r = 0; r < 4; ++r){
                    const float gi = sigmoid_fast(acc[m][0][r]);
                    const float gf = sigmoid_fast(acc[m][1][r]);
                    const float gg = tanh_fast  (acc[m][2][r]);
                    const float go = sigmoid_fast(acc[m][3][r]);
                    const float c_ = gf * cst[mt][r] + gi * gg;
                    cst[mt][r] = c_;
                    hw[mt * 16 + quad * 4 + r][w * 16 + col] = f2bf(go * tanh_fast(c_));
                }
            }
        }
    }
    __syncthreads();

    // ---- output projection from final h (bf16, in h buffer 0) ----
    const short (*hfin)[72] = (const short(*)[72])(smem + H_OFF(0));
    for (int idx = tid; idx < BT * O_DIM; idx += 256){
        const int m = idx / O_DIM;
        const int o = idx - m * O_DIM;
        float s = bout_s[o];
        #pragma unroll 8
        for (int j = 0; j < H_DIM; ++j)
            s += bf2f(hfin[m][j]) * wout_t[j * O_DIM + o];
        out[(size_t)b0 * O_DIM + idx] = s;
    }
}

extern "C" void kernel_launch(void* const* d_in, const int* in_sizes, int n_in,
                              void* d_out, int out_size, void* d_ws, size_t ws_size,
                              hipStream_t stream) {
    const float* x     = (const float*)d_in[0];
    const float* W_ih  = (const float*)d_in[1];
    const float* W_hh  = (const float*)d_in[2];
    const float* b_ih  = (const float*)d_in[3];
    const float* b_hh  = (const float*)d_in[4];
    const float* W_out = (const float*)d_in[5];
    const float* b_out = (const float*)d_in[6];
    float* out = (float*)d_out;

    const int grid = 65536 / BT;   // 1024 blocks
    lstm_fused<<<grid, 256, 0, stream>>>(x, W_ih, W_hh, b_ih, b_hh, W_out, b_out, out);
}

// Round 4
// 387.136 us; speedup vs baseline: 2.3560x; 2.3560x over previous
//
#include <hip/hip_runtime.h>
#include <hip/hip_bf16.h>
#include <stdint.h>
#include <stddef.h>

#define T_STEPS 28
#define I_DIM 28
#define H_DIM 64
#define O_DIM 10
#define BT 64    // batch rows per block
#define NTHREADS 512

typedef short bf16x8 __attribute__((ext_vector_type(8)));
typedef float f32x4  __attribute__((ext_vector_type(4)));

__device__ __forceinline__ short f2bf(float f){
    uint32_t u = __builtin_bit_cast(uint32_t, f);
    u = (u + 0x7fffu + ((u >> 16) & 1u)) >> 16;
    return (short)u;
}
__device__ __forceinline__ float bf2f(short v){
    return __builtin_bit_cast(float, (uint32_t)(uint16_t)v << 16);
}
__device__ __forceinline__ float sigmoid_fast(float x){
    return __builtin_amdgcn_rcpf(1.0f + __builtin_amdgcn_exp2f(-1.4426950408889634f * x));
}
__device__ __forceinline__ float tanh_fast(float x){
    return 1.0f - 2.0f * __builtin_amdgcn_rcpf(1.0f + __builtin_amdgcn_exp2f(2.8853900817779268f * x));
}

// LDS layout (bytes):
//   x0: short[64][40] @ 0      (5120)   x tile, t even
//   x1: short[64][40] @ 5120   (5120)   x tile, t odd
//   h0: short[64][72] @ 10240  (9216)   h buffer 0 (final h lands here: 28 steps -> buf 0)
//   h1: short[64][72] @ 19456  (9216)   h buffer 1
//   wout_t: float[640] @ 28672 (2560)
//   bout_s: float[12]  @ 31232 (48)
#define X_OFF(b)  ((b) * 5120)
#define H_OFF(b)  (10240 + (b) * 9216)
#define SMEM_BYTES (31232 + 48)

__global__ __launch_bounds__(NTHREADS, 4)
void lstm_fused(const float* __restrict__ x,
                const float* __restrict__ W_ih,
                const float* __restrict__ W_hh,
                const float* __restrict__ b_ih,
                const float* __restrict__ b_hh,
                const float* __restrict__ W_out,
                const float* __restrict__ b_out,
                float* __restrict__ out)
{
    __shared__ alignas(16) unsigned char smem[SMEM_BYTES];
    float* wout_t = (float*)(smem + 28672);
    float* bout_s = (float*)(smem + 31232);

    const int tid    = threadIdx.x;
    const int w      = tid >> 6;      // wave 0..7
    const int jgroup = w & 3;         // hidden-col tile: j in [16*jgroup, 16*jgroup+16)
    const int mgroup = w >> 2;        // m-tile pair: mt in {2*mgroup, 2*mgroup+1}
    const int lane = tid & 63;
    const int col  = lane & 15;
    const int quad = lane >> 4;
    const int b0   = blockIdx.x * BT;

    // ---- weight B-fragments in registers (once) ----
    // B[k][n]: lane holds n = nt*64 + jgroup*16 + col, k = quad*8 + j
    bf16x8 wih[4];
    bf16x8 whh[2][4];
    float  bias_v[4];
    #pragma unroll
    for (int nt = 0; nt < 4; ++nt){
        const int n = nt * 64 + jgroup * 16 + col;
        #pragma unroll
        for (int j = 0; j < 8; ++j){
            const int k = quad * 8 + j;
            wih[nt][j] = (k < I_DIM) ? f2bf(W_ih[n * I_DIM + k]) : (short)0;
        }
        #pragma unroll
        for (int s = 0; s < 2; ++s)
            #pragma unroll
            for (int j = 0; j < 8; ++j){
                const int k = s * 32 + quad * 8 + j;
                whh[s][nt][j] = f2bf(W_hh[n * H_DIM + k]);
            }
        bias_v[nt] = b_ih[n] + b_hh[n];
    }

    // ---- stage W_out (transposed) + b_out ----
    for (int idx = tid; idx < H_DIM * O_DIM; idx += NTHREADS){
        const int j = idx / O_DIM;
        const int o = idx - j * O_DIM;
        wout_t[idx] = W_out[o * H_DIM + j];
    }
    if (tid < O_DIM) bout_s[tid] = b_out[tid];

    // ---- zero h buffer 0 (initial state) ----
    for (int idx = tid; idx < 64 * 72; idx += NTHREADS)
        ((short*)(smem + H_OFF(0)))[idx] = 0;

    // ---- x staging: 8 threads per row, 4 cols each (cols 28..31 write zeros) ----
    const int row = tid >> 3;
    const int seg = tid & 7;
    const float* px = x + (size_t)(b0 + row) * (T_STEPS * I_DIM);

    float xa[4];
    #pragma unroll
    for (int u = 0; u < 4; ++u){
        const int k = seg * 4 + u;
        xa[u] = (k < I_DIM) ? px[k] : 0.0f;   // seg 7 stays 0 forever (pad cols)
    }

    float cst[2][4];
    #pragma unroll
    for (int m = 0; m < 2; ++m)
        #pragma unroll
        for (int r = 0; r < 4; ++r) cst[m][r] = 0.0f;

    for (int t = 0; t < T_STEPS; ++t){
        short (*xb)[40] = (short(*)[40])(smem + X_OFF(t & 1));
        // stage x(t) (packed bf16x2 b32 stores)
        #pragma unroll
        for (int u = 0; u < 2; ++u){
            float2 p2; p2.x = xa[2*u]; p2.y = xa[2*u+1];
            __hip_bfloat162 p = __float22bfloat162_rn(p2);
            *(__hip_bfloat162*)&xb[row][seg * 4 + 2 * u] = p;
        }
        // prefetch x(t+1) — latency hides behind this step's compute
        if (t < T_STEPS - 1){
            #pragma unroll
            for (int u = 0; u < 4; ++u){
                const int k = seg * 4 + u;
                if (k < I_DIM) xa[u] = px[(t + 1) * I_DIM + k];
            }
        }
        __syncthreads();   // single barrier per step: x(t) staged, h(t-1) visible

        const short (*hr)[72] = (const short(*)[72])(smem + H_OFF(t & 1));
        short (*hw)[72]       = (short(*)[72])(smem + H_OFF((t + 1) & 1));

        // one m-tile at a time -> acc live range is 16 regs
        #pragma unroll
        for (int m = 0; m < 2; ++m){
            const int mt = mgroup * 2 + m;

            f32x4 acc[4];
            #pragma unroll
            for (int nt = 0; nt < 4; ++nt){
                f32x4 c4;
                c4[0] = bias_v[nt]; c4[1] = bias_v[nt]; c4[2] = bias_v[nt]; c4[3] = bias_v[nt];
                acc[nt] = c4;
            }

            // x-projection: [16 x 32] @ [32 x 64(this wave's cols x gates)]
            {
                bf16x8 a = *(const bf16x8*)&xb[mt * 16 + col][quad * 8];
                #pragma unroll
                for (int nt = 0; nt < 4; ++nt)
                    acc[nt] = __builtin_amdgcn_mfma_f32_16x16x32_bf16(a, wih[nt], acc[nt], 0, 0, 0);
            }
            // recurrence: [16 x 64] @ [64 x 64]
            #pragma unroll
            for (int s = 0; s < 2; ++s){
                bf16x8 a = *(const bf16x8*)&hr[mt * 16 + col][s * 32 + quad * 8];
                #pragma unroll
                for (int nt = 0; nt < 4; ++nt)
                    acc[nt] = __builtin_amdgcn_mfma_f32_16x16x32_bf16(a, whh[s][nt], acc[nt], 0, 0, 0);
            }

            // activations + cell update; write h to the write buffer
            #pragma unroll
            for (int r = 0; r < 4; ++r){
                const float gi = sigmoid_fast(acc[0][r]);
                const float gf = sigmoid_fast(acc[1][r]);
                const float gg = tanh_fast  (acc[2][r]);
                const float go = sigmoid_fast(acc[3][r]);
                const float c_ = gf * cst[m][r] + gi * gg;
                cst[m][r] = c_;
                hw[mt * 16 + quad * 4 + r][jgroup * 16 + col] = f2bf(go * tanh_fast(c_));
            }
        }
    }
    __syncthreads();

    // ---- output projection from final h (bf16, in h buffer 0) ----
    const short (*hfin)[72] = (const short(*)[72])(smem + H_OFF(0));
    for (int idx = tid; idx < BT * O_DIM; idx += NTHREADS){
        const int m = idx / O_DIM;
        const int o = idx - m * O_DIM;
        float s = bout_s[o];
        #pragma unroll 8
        for (int j = 0; j < H_DIM; ++j)
            s += bf2f(hfin[m][j]) * wout_t[j * O_DIM + o];
        out[(size_t)b0 * O_DIM + idx] = s;
    }
}

extern "C" void kernel_launch(void* const* d_in, const int* in_sizes, int n_in,
                              void* d_out, int out_size, void* d_ws, size_t ws_size,
                              hipStream_t stream) {
    const float* x     = (const float*)d_in[0];
    const float* W_ih  = (const float*)d_in[1];
    const float* W_hh  = (const float*)d_in[2];
    const float* b_ih  = (const float*)d_in[3];
    const float* b_hh  = (const float*)d_in[4];
    const float* W_out = (const float*)d_in[5];
    const float* b_out = (const float*)d_in[6];
    float* out = (float*)d_out;

    const int grid = 65536 / BT;   // 1024 blocks x 512 threads
    lstm_fused<<<grid, NTHREADS, 0, stream>>>(x, W_ih, W_hh, b_ih, b_hh, W_out, b_out, out);
}

// Round 6
// 382.195 us; speedup vs baseline: 2.3865x; 1.0129x over previous
//
#include <hip/hip_runtime.h>
#include <hip/hip_bf16.h>
#include <stdint.h>
#include <stddef.h>

#define T_STEPS 28
#define I_DIM 28
#define H_DIM 64
#define O_DIM 10
#define BT 64    // batch rows per block
#define NTHREADS 512

typedef short bf16x8  __attribute__((ext_vector_type(8)));
typedef float f32x4   __attribute__((ext_vector_type(4)));

// exp2 scale constants folded into weights:
//   sigmoid(z) = rcp(1 + exp2(-log2e * z))      -> scale i,f,o rows by KS
//   tanh(z)    = 1 - 2*rcp(1 + exp2(2*log2e*z)) -> scale g rows by KG
#define KS (-1.4426950408889634f)
#define KG ( 2.8853900817779268f)

__device__ __forceinline__ short f2bf(float f){
    uint32_t u = __builtin_bit_cast(uint32_t, f);
    u = (u + 0x7fffu + ((u >> 16) & 1u)) >> 16;
    return (short)u;
}
__device__ __forceinline__ float bf2f(short v){
    return __builtin_bit_cast(float, (uint32_t)(uint16_t)v << 16);
}
// packed f32x2 -> bf16x2 (RNE) as raw bits; memcpy dodges the non-trivially-
// copyable __hip_bfloat162 (compiles to a plain register move)
__device__ __forceinline__ uint32_t pack_bf16x2(float lo, float hi){
    float2 p2; p2.x = lo; p2.y = hi;
    __hip_bfloat162 p = __float22bfloat162_rn(p2);
    uint32_t u;
    __builtin_memcpy(&u, &p, 4);
    return u;
}

// LDS layout (bytes):
//   x0: short[64][40] @ 0      (5120)
//   x1: short[64][40] @ 5120   (5120)
//   h0: short[64][72] @ 10240  (9216)  (final h lands here after 28 steps)
//   h1: short[64][72] @ 19456  (9216)
//   wout_t: float[640] @ 28672 (2560)
//   bout_s: float[12]  @ 31232 (48)
#define X_OFF(b)  ((b) * 5120)
#define H_OFF(b)  (10240 + (b) * 9216)
#define SMEM_BYTES (31232 + 48)

__global__ __launch_bounds__(NTHREADS, 4)
void lstm_fused(const float* __restrict__ x,
                const float* __restrict__ W_ih,
                const float* __restrict__ W_hh,
                const float* __restrict__ b_ih,
                const float* __restrict__ b_hh,
                const float* __restrict__ W_out,
                const float* __restrict__ b_out,
                float* __restrict__ out)
{
    __shared__ alignas(16) unsigned char smem[SMEM_BYTES];
    float* wout_t = (float*)(smem + 28672);
    float* bout_s = (float*)(smem + 31232);

    const int tid    = threadIdx.x;
    const int w      = tid >> 6;      // wave 0..7
    const int jgroup = w & 3;         // hidden-col tile: j in [16*jgroup, 16*jgroup+16)
    const int mgroup = w >> 2;        // m-tile pair: mt in {2*mgroup, 2*mgroup+1}
    const int lane = tid & 63;
    const int col  = lane & 15;
    const int quad = lane >> 4;
    const int jcol = jgroup * 16 + col;
    const int b0   = blockIdx.x * BT;

    // ---- weight B-fragments in registers, pre-scaled by exp2 constants ----
    // B[k][n]: lane holds n = nt*64 + jgroup*16 + col, k = quad*8 + j
    bf16x8 wih[4];
    bf16x8 whh[2][4];
    f32x4  bias4[4];           // replicated bias -> direct C operand of first MFMA
    #pragma unroll
    for (int nt = 0; nt < 4; ++nt){
        const float sc = (nt == 2) ? KG : KS;
        const int n = nt * 64 + jgroup * 16 + col;
        #pragma unroll
        for (int j = 0; j < 8; ++j){
            const int k = quad * 8 + j;
            wih[nt][j] = (k < I_DIM) ? f2bf(sc * W_ih[n * I_DIM + k]) : (short)0;
        }
        #pragma unroll
        for (int s = 0; s < 2; ++s)
            #pragma unroll
            for (int j = 0; j < 8; ++j){
                const int k = s * 32 + quad * 8 + j;
                whh[s][nt][j] = f2bf(sc * W_hh[n * H_DIM + k]);
            }
        const float b = sc * (b_ih[n] + b_hh[n]);
        f32x4 bv; bv[0] = b; bv[1] = b; bv[2] = b; bv[3] = b;
        bias4[nt] = bv;
    }

    // ---- stage W_out (transposed) + b_out ----
    for (int idx = tid; idx < H_DIM * O_DIM; idx += NTHREADS){
        const int j = idx / O_DIM;
        const int o = idx - j * O_DIM;
        wout_t[idx] = W_out[o * H_DIM + j];
    }
    if (tid < O_DIM) bout_s[tid] = b_out[tid];

    // ---- zero h buffer 0 (initial state) ----
    for (int idx = tid; idx < 64 * 72; idx += NTHREADS)
        ((short*)(smem + H_OFF(0)))[idx] = 0;

    // ---- x staging: 8 threads per row, 4 cols each (cols 28..31 write zeros) ----
    const int row = tid >> 3;
    const int seg = tid & 7;
    const float* pxs = x + (size_t)(b0 + row) * (T_STEPS * I_DIM) + seg * 4;

    float xa[4];
    #pragma unroll
    for (int u = 0; u < 4; ++u)
        xa[u] = (seg * 4 + u < I_DIM) ? pxs[u] : 0.0f;   // seg 7 pad stays 0 forever
    pxs += I_DIM;

    float cst[2][4];
    #pragma unroll
    for (int m = 0; m < 2; ++m)
        #pragma unroll
        for (int r = 0; r < 4; ++r) cst[m][r] = 0.0f;

    for (int t = 0; t < T_STEPS; ++t){
        short (*xb)[40] = (short(*)[40])(smem + X_OFF(t & 1));
        // stage x(t): packed cvt + one b64 LDS store
        {
            uint2 v;
            v.x = pack_bf16x2(xa[0], xa[1]);
            v.y = pack_bf16x2(xa[2], xa[3]);
            *(uint2*)&xb[row][seg * 4] = v;
        }
        __syncthreads();   // single barrier per step; no vmcnt pending here

        // prefetch x(t+1) AFTER the barrier: stays in flight across compute
        if (t < T_STEPS - 1){
            #pragma unroll
            for (int u = 0; u < 4; ++u)
                if (seg * 4 + u < I_DIM) xa[u] = pxs[u];
            pxs += I_DIM;
        }

        const short (*hr)[72] = (const short(*)[72])(smem + H_OFF(t & 1));
        short (*hw)[72]       = (short(*)[72])(smem + H_OFF((t + 1) & 1));

        #pragma unroll
        for (int m = 0; m < 2; ++m){
            const int mt = mgroup * 2 + m;

            // x-projection with bias as the C operand (no acc-init movs)
            f32x4 acc[4];
            {
                bf16x8 a = *(const bf16x8*)&xb[mt * 16 + col][quad * 8];
                #pragma unroll
                for (int nt = 0; nt < 4; ++nt)
                    acc[nt] = __builtin_amdgcn_mfma_f32_16x16x32_bf16(a, wih[nt], bias4[nt], 0, 0, 0);
            }
            // recurrence
            #pragma unroll
            for (int s = 0; s < 2; ++s){
                bf16x8 a = *(const bf16x8*)&hr[mt * 16 + col][s * 32 + quad * 8];
                #pragma unroll
                for (int nt = 0; nt < 4; ++nt)
                    acc[nt] = __builtin_amdgcn_mfma_f32_16x16x32_bf16(a, whh[s][nt], acc[nt], 0, 0, 0);
            }

            // activations (weights pre-scaled -> no arg muls) + cell update
            float hv[4];
            #pragma unroll
            for (int r = 0; r < 4; ++r){
                const float gi = __builtin_amdgcn_rcpf(1.0f + __builtin_amdgcn_exp2f(acc[0][r]));
                const float gf = __builtin_amdgcn_rcpf(1.0f + __builtin_amdgcn_exp2f(acc[1][r]));
                const float rg = __builtin_amdgcn_rcpf(1.0f + __builtin_amdgcn_exp2f(acc[2][r]));
                const float gg = 1.0f - 2.0f * rg;
                const float go = __builtin_amdgcn_rcpf(1.0f + __builtin_amdgcn_exp2f(acc[3][r]));
                const float c_ = gf * cst[m][r] + gi * gg;
                cst[m][r] = c_;
                const float rc = __builtin_amdgcn_rcpf(1.0f + __builtin_amdgcn_exp2f(KG * c_));
                hv[r] = go * (1.0f - 2.0f * rc);
            }
            // packed conversion, two b16 stores per pair (rows differ by 1)
            #pragma unroll
            for (int rp = 0; rp < 2; ++rp){
                uint32_t u = pack_bf16x2(hv[2 * rp], hv[2 * rp + 1]);
                hw[mt * 16 + quad * 4 + 2 * rp    ][jcol] = (short)(u & 0xffffu);
                hw[mt * 16 + quad * 4 + 2 * rp + 1][jcol] = (short)(u >> 16);
            }
        }
    }
    __syncthreads();

    // ---- output projection from final h (bf16, in h buffer 0) ----
    const short (*hfin)[72] = (const short(*)[72])(smem + H_OFF(0));
    for (int idx = tid; idx < BT * O_DIM; idx += NTHREADS){
        const int m = idx / O_DIM;
        const int o = idx - m * O_DIM;
        float s = bout_s[o];
        #pragma unroll 8
        for (int j = 0; j < H_DIM; ++j)
            s += bf2f(hfin[m][j]) * wout_t[j * O_DIM + o];
        out[(size_t)b0 * O_DIM + idx] = s;
    }
}

extern "C" void kernel_launch(void* const* d_in, const int* in_sizes, int n_in,
                              void* d_out, int out_size, void* d_ws, size_t ws_size,
                              hipStream_t stream) {
    const float* x     = (const float*)d_in[0];
    const float* W_ih  = (const float*)d_in[1];
    const float* W_hh  = (const float*)d_in[2];
    const float* b_ih  = (const float*)d_in[3];
    const float* b_hh  = (const float*)d_in[4];
    const float* W_out = (const float*)d_in[5];
    const float* b_out = (const float*)d_in[6];
    float* out = (float*)d_out;

    const int grid = 65536 / BT;   // 1024 blocks x 512 threads
    lstm_fused<<<grid, NTHREADS, 0, stream>>>(x, W_ih, W_hh, b_ih, b_hh, W_out, b_out, out);
}